// Round 1
// baseline (99.768 us; speedup 1.0000x reference)
//
#include <hip/hip_runtime.h>
#include <stdint.h>

typedef short bf16x8 __attribute__((ext_vector_type(8)));
typedef float f32x4 __attribute__((ext_vector_type(4)));

#define NROWS 8192
#define DIM   128
// sqrt(10/ln2): dot of scaled z gives 10*cos/ln2, so exp2(dot)=exp(10*cos)
#define ZSCALE 3.7982824f
#define LN2F  0.6931471805599453f

__device__ __forceinline__ unsigned short f32_to_bf16_bits(float x) {
  union { float f; uint32_t u; } v; v.f = x;
  uint32_t r = v.u + 0x7FFFu + ((v.u >> 16) & 1u);  // RNE
  return (unsigned short)(r >> 16);
}

#define GLOAD_LDS16(gsrc, ldst)                                      \
  __builtin_amdgcn_global_load_lds(                                  \
      (const __attribute__((address_space(1))) unsigned int*)(gsrc), \
      (__attribute__((address_space(3))) unsigned int*)(ldst), 16, 0, 0)

// K1: z = bf16( ZSCALE * normalize(anchor @ W + bias) )
// 128 blocks x 256 thr; wave w owns 16 output rows (rowbase..+15), all 128 cols.
__global__ __launch_bounds__(256) void k_proj_norm(
    const float* __restrict__ anchor, const float* __restrict__ W,
    const float* __restrict__ bias, unsigned short* __restrict__ z) {
  const int t = threadIdx.x;
  const int wv = t >> 6, l = t & 63, g = l >> 4, q = l & 15;
  const int rowbase = blockIdx.x * 64 + wv * 16;

  f32x4 acc[8];
#pragma unroll
  for (int tj = 0; tj < 8; ++tj) acc[tj] = (f32x4){0.f, 0.f, 0.f, 0.f};

#pragma unroll
  for (int ks = 0; ks < 4; ++ks) {
    // A frag: lane holds anchor[rowbase+q][ks*32+g*8 .. +8]
    const float* ap = anchor + (size_t)(rowbase + q) * DIM + ks * 32 + g * 8;
    bf16x8 a;
#pragma unroll
    for (int e = 0; e < 8; ++e) a[e] = (short)f32_to_bf16_bits(ap[e]);
#pragma unroll
    for (int tj = 0; tj < 8; ++tj) {
      // B frag: lane holds W[ks*32+g*8+e][tj*16+q] (column gather, L1-resident 64KB)
      const float* wp = W + (size_t)(ks * 32 + g * 8) * DIM + tj * 16 + q;
      bf16x8 bfr;
#pragma unroll
      for (int e = 0; e < 8; ++e) bfr[e] = (short)f32_to_bf16_bits(wp[(size_t)e * DIM]);
      acc[tj] = __builtin_amdgcn_mfma_f32_16x16x32_bf16(a, bfr, acc[tj], 0, 0, 0);
    }
  }

  // C/D layout: col = q, row = 4*g + r  (verified m89/m91)
  float sumsq[4] = {0.f, 0.f, 0.f, 0.f};
#pragma unroll
  for (int tj = 0; tj < 8; ++tj) {
    float bv = bias[tj * 16 + q];
#pragma unroll
    for (int r = 0; r < 4; ++r) {
      acc[tj][r] += bv;
      sumsq[r] += acc[tj][r] * acc[tj][r];
    }
  }
  // reduce over the 16 col-lanes of each group (masks stay inside the group)
#pragma unroll
  for (int r = 0; r < 4; ++r) {
#pragma unroll
    for (int m = 1; m < 16; m <<= 1) sumsq[r] += __shfl_xor(sumsq[r], m, 64);
  }
  float inv[4];
#pragma unroll
  for (int r = 0; r < 4; ++r) inv[r] = ZSCALE / fmaxf(sqrtf(sumsq[r]), 1e-12f);

#pragma unroll
  for (int tj = 0; tj < 8; ++tj)
#pragma unroll
    for (int r = 0; r < 4; ++r)
      z[(size_t)(rowbase + 4 * g + r) * DIM + tj * 16 + q] =
          f32_to_bf16_bits(acc[tj][r] * inv[r]);
}

// K2: fused Z @ Z^T -> exp2 -> row sums (+ diag skip, + positive-pair capture)
// grid = 128 i-blocks (64 rows) * 8 j-slices; block = 4 waves side-by-side in j.
// Per chunk (128 j-rows) staged in LDS with XOR swizzle (c ^= row&7 on 16B cols).
__global__ __launch_bounds__(256) void k_simloss(
    const unsigned short* __restrict__ z, float* __restrict__ sumexp,
    float* __restrict__ topacc) {
  __shared__ __align__(16) unsigned short lz[128 * 128];  // 32 KB
  const int t = threadIdx.x;
  const int wv = t >> 6, l = t & 63, g = l >> 4, q = l & 15;
  const int iblk = (int)blockIdx.x >> 3, slice = (int)blockIdx.x & 7;
  const int ib = iblk * 64;

  // A frags: wave holds all 64 i-rows: afr[ti][ks], lane = row ib+ti*16+q, k = ks*32+g*8..+8
  bf16x8 afr[4][4];
#pragma unroll
  for (int ti = 0; ti < 4; ++ti)
#pragma unroll
    for (int ks = 0; ks < 4; ++ks)
      afr[ti][ks] =
          *(const bf16x8*)(z + (size_t)(ib + ti * 16 + q) * DIM + ks * 32 + g * 8);

  float sums[4][4];  // [ti][r] partial sum-of-exp over this lane's cols
#pragma unroll
  for (int ti = 0; ti < 4; ++ti)
#pragma unroll
    for (int r = 0; r < 4; ++r) sums[ti][r] = 0.f;
  float topv = 0.f;

  const int diag_chunk = iblk >> 1;
  const int pos_chunk = ((iblk >> 1) + 32) & 63;
  const int iloc_base = ib & 127;  // 0 or 64

  const int ch0 = slice * 8;
  for (int ch = ch0; ch < ch0 + 8; ++ch) {
    // ---- stage 128 j-rows (32 KB) via global_load_lds, swizzled source ----
#pragma unroll
    for (int it = 0; it < 8; ++it) {
      const int n = it * 256 + t;          // linear 16B slot
      const int row = n >> 4, c = n & 15;  // dest (row, col16)
      const char* src = (const char*)z + ((size_t)(ch * 128 + row) << 8) +
                        (((c ^ (row & 7)) << 4));
      GLOAD_LDS16(src, (char*)lz + it * 4096 + wv * 1024);  // wave-uniform dest
    }
    __syncthreads();

    // ---- MFMA: 64 i-rows x 32 j-cols per wave, K=128 ----
    f32x4 acc[4][2];
#pragma unroll
    for (int ti = 0; ti < 4; ++ti)
#pragma unroll
      for (int tj = 0; tj < 2; ++tj) acc[ti][tj] = (f32x4){0.f, 0.f, 0.f, 0.f};

#pragma unroll
    for (int tj = 0; tj < 2; ++tj) {
      const int row_l = wv * 32 + tj * 16 + q;
      bf16x8 bfr[4];
#pragma unroll
      for (int ks = 0; ks < 4; ++ks) {
        const int c = ks * 4 + g;
        bfr[ks] = *(const bf16x8*)((const char*)lz + row_l * 256 +
                                   ((c ^ (row_l & 7)) << 4));
      }
#pragma unroll
      for (int ti = 0; ti < 4; ++ti)
#pragma unroll
        for (int ks = 0; ks < 4; ++ks)
          acc[ti][tj] =
              __builtin_amdgcn_mfma_f32_16x16x32_bf16(afr[ti][ks], bfr[ks],
                                                      acc[ti][tj], 0, 0, 0);
    }

    // ---- epilogue: e = exp2(d); diag skip / positive capture in special chunks ----
    const bool dg = (ch == diag_chunk), ps = (ch == pos_chunk);
    if (dg || ps) {
#pragma unroll
      for (int ti = 0; ti < 4; ++ti)
#pragma unroll
        for (int tj = 0; tj < 2; ++tj)
#pragma unroll
          for (int r = 0; r < 4; ++r) {
            const float d = acc[ti][tj][r];
            const int iloc = iloc_base + ti * 16 + 4 * g + r;
            const int cloc = wv * 32 + tj * 16 + q;
            float e = exp2f(d);
            if (dg && cloc == iloc) e = 0.f;       // j == i: excluded from bottom
            if (ps && cloc == iloc) topv += d;     // j == (i+4096)%8192
            sums[ti][r] += e;
          }
    } else {
#pragma unroll
      for (int ti = 0; ti < 4; ++ti)
#pragma unroll
        for (int tj = 0; tj < 2; ++tj)
#pragma unroll
          for (int r = 0; r < 4; ++r) sums[ti][r] += exp2f(acc[ti][tj][r]);
    }
    __syncthreads();  // protect LDS before next stage
  }

  // reduce partial row-sums across the 16 col-lanes of each group
#pragma unroll
  for (int ti = 0; ti < 4; ++ti)
#pragma unroll
    for (int r = 0; r < 4; ++r) {
#pragma unroll
      for (int m = 1; m < 16; m <<= 1)
        sums[ti][r] += __shfl_xor(sums[ti][r], m, 64);
    }
  if (q == 0) {
#pragma unroll
    for (int ti = 0; ti < 4; ++ti)
#pragma unroll
      for (int r = 0; r < 4; ++r)
        atomicAdd(&sumexp[ib + ti * 16 + 4 * g + r], sums[ti][r]);
  }

  // top-term: full wave reduce, one atomic per wave
#pragma unroll
  for (int m = 1; m < 64; m <<= 1) topv += __shfl_xor(topv, m, 64);
  if (l == 0) atomicAdd(topacc, topv);
}

// K3: loss = (sum_i ln(bottom_i) - ln2 * sum_top) / (b-1)
__global__ __launch_bounds__(256) void k_final(const float* __restrict__ sumexp,
                                               const float* __restrict__ topacc,
                                               float* __restrict__ out) {
  __shared__ float red[4];
  const int t = threadIdx.x;
  float s = 0.f;
  for (int r = t; r < NROWS; r += 256) s += logf(sumexp[r]);
#pragma unroll
  for (int m = 1; m < 64; m <<= 1) s += __shfl_xor(s, m, 64);
  if ((t & 63) == 0) red[t >> 6] = s;
  __syncthreads();
  if (t == 0) {
    const float S1 = red[0] + red[1] + red[2] + red[3];
    out[0] = (S1 - LN2F * topacc[0]) * (1.0f / (float)(NROWS - 1));
  }
}

extern "C" void kernel_launch(void* const* d_in, const int* in_sizes, int n_in,
                              void* d_out, int out_size, void* d_ws, size_t ws_size,
                              hipStream_t stream) {
  const float* anchor = (const float*)d_in[0];
  const float* W = (const float*)d_in[1];
  const float* bias = (const float*)d_in[2];
  float* out = (float*)d_out;

  char* ws = (char*)d_ws;
  unsigned short* z = (unsigned short*)ws;                       // 2 MB bf16 [8192][128]
  float* sumexp = (float*)(ws + (size_t)2 * 1024 * 1024);        // 32 KB
  float* topacc = (float*)(ws + (size_t)2 * 1024 * 1024 + 32768); // 4 B

  hipMemsetAsync(sumexp, 0, NROWS * sizeof(float) + sizeof(float), stream);
  k_proj_norm<<<dim3(NROWS / 64), dim3(256), 0, stream>>>(anchor, W, bias, z);
  k_simloss<<<dim3((NROWS / 64) * 8), dim3(256), 0, stream>>>(z, sumexp, topacc);
  k_final<<<dim3(1), dim3(256), 0, stream>>>(sumexp, topacc, out);
}

// Round 2
// 64.766 us; speedup vs baseline: 1.5404x; 1.5404x over previous
//
#include <hip/hip_runtime.h>
#include <stdint.h>

typedef short bf16x8 __attribute__((ext_vector_type(8)));
typedef float f32x4 __attribute__((ext_vector_type(4)));

#define NROWS 8192
#define DIM   128
// sqrt(10/ln2): dot of scaled z gives 10*cos/ln2, so exp2(dot)=exp(10*cos)
#define ZSCALE 3.7982824f
#define LN2F  0.6931471805599453f

__device__ __forceinline__ unsigned short f32_to_bf16_bits(float x) {
  union { float f; uint32_t u; } v; v.f = x;
  uint32_t r = v.u + 0x7FFFu + ((v.u >> 16) & 1u);  // RNE
  return (unsigned short)(r >> 16);
}

#define GLOAD_LDS16(gsrc, ldst)                                      \
  __builtin_amdgcn_global_load_lds(                                  \
      (const __attribute__((address_space(1))) unsigned int*)(gsrc), \
      (__attribute__((address_space(3))) unsigned int*)(ldst), 16, 0, 0)

// K1: z = bf16( ZSCALE * normalize(anchor @ W + bias) );  also zeroes sumexp/topacc.
// 128 blocks x 256 thr; wave w owns 16 output rows (rowbase..+15), all 128 cols.
__global__ __launch_bounds__(256) void k_proj_norm(
    const float* __restrict__ anchor, const float* __restrict__ W,
    const float* __restrict__ bias, unsigned short* __restrict__ z,
    float* __restrict__ sumexp, float* __restrict__ topacc) {
  const int t = threadIdx.x;
  // fold the accumulator zeroing in here (saves a memset dispatch)
  if (t < 64) sumexp[blockIdx.x * 64 + t] = 0.f;
  if (blockIdx.x == 0 && t == 64) topacc[0] = 0.f;

  const int wv = t >> 6, l = t & 63, g = l >> 4, q = l & 15;
  const int rowbase = blockIdx.x * 64 + wv * 16;

  f32x4 acc[8];
#pragma unroll
  for (int tj = 0; tj < 8; ++tj) acc[tj] = (f32x4){0.f, 0.f, 0.f, 0.f};

#pragma unroll
  for (int ks = 0; ks < 4; ++ks) {
    // A frag: lane holds anchor[rowbase+q][ks*32+g*8 .. +8]
    const float* ap = anchor + (size_t)(rowbase + q) * DIM + ks * 32 + g * 8;
    bf16x8 a;
#pragma unroll
    for (int e = 0; e < 8; ++e) a[e] = (short)f32_to_bf16_bits(ap[e]);
#pragma unroll
    for (int tj = 0; tj < 8; ++tj) {
      // B frag: lane holds W[ks*32+g*8+e][tj*16+q] (column gather, L1-resident 64KB)
      const float* wp = W + (size_t)(ks * 32 + g * 8) * DIM + tj * 16 + q;
      bf16x8 bfr;
#pragma unroll
      for (int e = 0; e < 8; ++e) bfr[e] = (short)f32_to_bf16_bits(wp[(size_t)e * DIM]);
      acc[tj] = __builtin_amdgcn_mfma_f32_16x16x32_bf16(a, bfr, acc[tj], 0, 0, 0);
    }
  }

  // C/D layout: col = q, row = 4*g + r
  float sumsq[4] = {0.f, 0.f, 0.f, 0.f};
#pragma unroll
  for (int tj = 0; tj < 8; ++tj) {
    float bv = bias[tj * 16 + q];
#pragma unroll
    for (int r = 0; r < 4; ++r) {
      acc[tj][r] += bv;
      sumsq[r] += acc[tj][r] * acc[tj][r];
    }
  }
#pragma unroll
  for (int r = 0; r < 4; ++r) {
#pragma unroll
    for (int m = 1; m < 16; m <<= 1) sumsq[r] += __shfl_xor(sumsq[r], m, 64);
  }
  float inv[4];
#pragma unroll
  for (int r = 0; r < 4; ++r) inv[r] = ZSCALE / fmaxf(sqrtf(sumsq[r]), 1e-12f);

#pragma unroll
  for (int tj = 0; tj < 8; ++tj)
#pragma unroll
    for (int r = 0; r < 4; ++r)
      z[(size_t)(rowbase + 4 * g + r) * DIM + tj * 16 + q] =
          f32_to_bf16_bits(acc[tj][r] * inv[r]);
}

// K2: fused Z @ Z^T -> exp2 -> row sums (+ diag skip, + positive-pair capture)
// grid = 64 i-blocks (128 rows) * 8 j-slices of 8 chunks; 4 waves SPLIT I:
// wave wv owns rows [ib+wv*32, +32), all waves consume the full 128-row LDS
// chunk (4x reuse). Double-buffered LDS (2x32KB), 2-phase pipeline:
// issue STAGE(next) -> compute(cur) -> syncthreads (vmcnt drain) -> swap.
__global__ __launch_bounds__(256) void k_simloss(
    const unsigned short* __restrict__ z, float* __restrict__ sumexp,
    float* __restrict__ topacc) {
  __shared__ __align__(16) unsigned short lz[2 * 128 * 128];  // 2 x 32 KB
  const int t = threadIdx.x;
  const int wv = t >> 6, l = t & 63, g = l >> 4, q = l & 15;
  const int iblk = (int)blockIdx.x >> 3, slice = (int)blockIdx.x & 7;
  const int ib = iblk * 128;

  // A frags: wave holds its 32 i-rows: lane = row ib+wv*32+ti*16+q, k = ks*32+g*8..+8
  bf16x8 afr[2][4];
#pragma unroll
  for (int ti = 0; ti < 2; ++ti)
#pragma unroll
    for (int ks = 0; ks < 4; ++ks)
      afr[ti][ks] = *(const bf16x8*)(z + (size_t)(ib + wv * 32 + ti * 16 + q) * DIM +
                                     ks * 32 + g * 8);

  float sums[2][4];  // [ti][r] partial sum-of-exp over this lane's cols
#pragma unroll
  for (int ti = 0; ti < 2; ++ti)
#pragma unroll
    for (int r = 0; r < 4; ++r) sums[ti][r] = 0.f;
  float topv = 0.f;

  const int diag_chunk = iblk;                 // 128-row iblock == 128-col chunk
  const int pos_chunk = (iblk + 32) & 63;      // +4096 cols = +32 chunks
  const int ch0 = slice * 8;

// stage chunk ch_ into LDS buffer at byte offset bufofs (linear dest, swizzled src)
#define STAGE(bufofs, ch_)                                                   \
  _Pragma("unroll") for (int it = 0; it < 8; ++it) {                         \
    const int n = it * 256 + t;                                              \
    const int row = n >> 4, c = n & 15;                                      \
    const char* src = (const char*)z + ((size_t)((ch_)*128 + row) << 8) +    \
                      ((c ^ (row & 7)) << 4);                                \
    GLOAD_LDS16(src, (char*)lz + (bufofs) + it * 4096 + wv * 1024);          \
  }

  STAGE(0, ch0);
  __syncthreads();  // vmcnt(0) drain: buf0 ready
  int cur = 0;

  for (int ch = ch0; ch < ch0 + 8; ++ch) {
    // ---- issue next chunk's loads into the other buffer (overlaps compute) ----
    if (ch + 1 < ch0 + 8) STAGE(cur ? 0 : 32768, ch + 1);

    // ---- MFMA: 32 i-rows x 128 j-cols per wave, K=128 ----
    f32x4 acc[2][8];
#pragma unroll
    for (int ti = 0; ti < 2; ++ti)
#pragma unroll
      for (int tj = 0; tj < 8; ++tj) acc[ti][tj] = (f32x4){0.f, 0.f, 0.f, 0.f};

    const char* buf = (const char*)lz + (cur ? 32768 : 0);
#pragma unroll
    for (int tj = 0; tj < 8; ++tj) {
      const int row_l = tj * 16 + q;
      bf16x8 bfr[4];
#pragma unroll
      for (int ks = 0; ks < 4; ++ks)
        bfr[ks] = *(const bf16x8*)(buf + row_l * 256 +
                                   (((ks * 4 + g) ^ (row_l & 7)) << 4));
#pragma unroll
      for (int ti = 0; ti < 2; ++ti)
#pragma unroll
        for (int ks = 0; ks < 4; ++ks)
          acc[ti][tj] = __builtin_amdgcn_mfma_f32_16x16x32_bf16(
              afr[ti][ks], bfr[ks], acc[ti][tj], 0, 0, 0);
    }

    // ---- epilogue: e = exp2(d); diag skip / positive capture in special chunks ----
    const bool dg = (ch == diag_chunk), ps = (ch == pos_chunk);
    if (dg || ps) {
#pragma unroll
      for (int ti = 0; ti < 2; ++ti)
#pragma unroll
        for (int tj = 0; tj < 8; ++tj)
#pragma unroll
          for (int r = 0; r < 4; ++r) {
            const float d = acc[ti][tj][r];
            const int iloc = wv * 32 + ti * 16 + 4 * g + r;
            const int cloc = tj * 16 + q;
            float e = __builtin_amdgcn_exp2f(d);
            if (dg && cloc == iloc) e = 0.f;    // j == i: excluded from bottom
            if (ps && cloc == iloc) topv += d;  // j == (i+4096)%8192
            sums[ti][r] += e;
          }
    } else {
#pragma unroll
      for (int ti = 0; ti < 2; ++ti)
#pragma unroll
        for (int tj = 0; tj < 8; ++tj)
#pragma unroll
          for (int r = 0; r < 4; ++r)
            sums[ti][r] += __builtin_amdgcn_exp2f(acc[ti][tj][r]);
    }

    __syncthreads();  // drains vmcnt(0): next buffer staged, all reads done
    cur ^= 1;
  }
#undef STAGE

  // reduce partial row-sums across the 16 col-lanes of each group
#pragma unroll
  for (int ti = 0; ti < 2; ++ti)
#pragma unroll
    for (int r = 0; r < 4; ++r) {
#pragma unroll
      for (int m = 1; m < 16; m <<= 1)
        sums[ti][r] += __shfl_xor(sums[ti][r], m, 64);
    }
  if (q == 0) {
#pragma unroll
    for (int ti = 0; ti < 2; ++ti)
#pragma unroll
      for (int r = 0; r < 4; ++r)
        atomicAdd(&sumexp[ib + wv * 32 + ti * 16 + 4 * g + r], sums[ti][r]);
  }

  // top-term: full wave reduce, one atomic per wave
#pragma unroll
  for (int m = 1; m < 64; m <<= 1) topv += __shfl_xor(topv, m, 64);
  if (l == 0) atomicAdd(topacc, topv);
}

// K3: loss = (sum_i ln(bottom_i) - ln2 * sum_top) / (b-1)
__global__ __launch_bounds__(256) void k_final(const float* __restrict__ sumexp,
                                               const float* __restrict__ topacc,
                                               float* __restrict__ out) {
  __shared__ float red[4];
  const int t = threadIdx.x;
  float s = 0.f;
  for (int r = t; r < NROWS; r += 256) s += logf(sumexp[r]);
#pragma unroll
  for (int m = 1; m < 64; m <<= 1) s += __shfl_xor(s, m, 64);
  if ((t & 63) == 0) red[t >> 6] = s;
  __syncthreads();
  if (t == 0) {
    const float S1 = red[0] + red[1] + red[2] + red[3];
    out[0] = (S1 - LN2F * topacc[0]) * (1.0f / (float)(NROWS - 1));
  }
}

extern "C" void kernel_launch(void* const* d_in, const int* in_sizes, int n_in,
                              void* d_out, int out_size, void* d_ws, size_t ws_size,
                              hipStream_t stream) {
  const float* anchor = (const float*)d_in[0];
  const float* W = (const float*)d_in[1];
  const float* bias = (const float*)d_in[2];
  float* out = (float*)d_out;

  char* ws = (char*)d_ws;
  unsigned short* z = (unsigned short*)ws;                        // 2 MB bf16 [8192][128]
  float* sumexp = (float*)(ws + (size_t)2 * 1024 * 1024);         // 32 KB
  float* topacc = (float*)(ws + (size_t)2 * 1024 * 1024 + 32768); // 4 B

  k_proj_norm<<<dim3(NROWS / 64), dim3(256), 0, stream>>>(anchor, W, bias, z,
                                                          sumexp, topacc);
  k_simloss<<<dim3((NROWS / 128) * 8), dim3(256), 0, stream>>>(z, sumexp, topacc);
  k_final<<<dim3(1), dim3(256), 0, stream>>>(sumexp, topacc, out);
}